// Round 1
// baseline (54.391 us; speedup 1.0000x reference)
//
#include <hip/hip_runtime.h>

#define EPSF 1e-5f

// Problem constants (from reference setup): B=8,E=16,N=64 -> 8192 series,
// T=128, D=32 hidden channels, OUT=64 output channels.
// Pipeline per series x[T]:
//   y1[d][t] = relu(inv1[d]*(conv1d(x,w1[d],pad=1)+b1[d]) + (beta1[d]-mean1[d]*inv1[d]))
//   y2[t]    = relu(s2*(sum_d conv1d(y1[d],w2[d],pad=1)+b2) + (beta2-mean2*s2))
//   out[o][t]= w3[o]*y2[t] + b3[o]
// Write-BW-bound: 256 MiB output, ~43us floor at 6.3 TB/s.

__global__ __launch_bounds__(128) void hnc_kernel(
    const float* __restrict__ x_in,   // [S][128]
    const float* __restrict__ w1,     // [32][1][3]
    const float* __restrict__ b1,     // [32]
    const float* __restrict__ w2,     // [1][32][3]
    const float* __restrict__ b2,     // [1]
    const float* __restrict__ w3,     // [64][1][1]
    const float* __restrict__ b3,     // [64]
    const float* __restrict__ g1, const float* __restrict__ be1,
    const float* __restrict__ m1, const float* __restrict__ v1,
    const float* __restrict__ g2, const float* __restrict__ be2,
    const float* __restrict__ m2, const float* __restrict__ v2,
    float* __restrict__ out)          // [S][64][128]
{
    const int T = 128, OUT = 64;

    __shared__ float x_s[130];          // zero halo at [0] and [129]
    __shared__ float y1_s[32 * 130];    // per-channel rows, zero halos
    __shared__ float y2_s[128];
    __shared__ float a1_s[3][32];       // BN1-folded conv1 weights
    __shared__ float c1_s[32];          // BN1-folded conv1 bias
    __shared__ float w2_s[3][32];       // BN2-scale-folded conv2 weights
    __shared__ float w3_s[64];
    __shared__ float b3_s[64];

    const int tid = threadIdx.x;        // = t position, 0..127
    const int series = blockIdx.x;

    // ---- Phase A: stage input + fold params into LDS ----
    x_s[1 + tid] = x_in[(size_t)series * T + tid];
    if (tid == 0) { x_s[0] = 0.f; x_s[129] = 0.f; }
    if (tid < 32) {
        float inv = g1[tid] * rsqrtf(v1[tid] + EPSF);
        a1_s[0][tid] = inv * w1[tid * 3 + 0];
        a1_s[1][tid] = inv * w1[tid * 3 + 1];
        a1_s[2][tid] = inv * w1[tid * 3 + 2];
        c1_s[tid] = b1[tid] * inv + be1[tid] - m1[tid] * inv;
    } else if (tid < 64) {
        int d = tid - 32;
        float s2 = g2[0] * rsqrtf(v2[0] + EPSF);
        w2_s[0][d] = s2 * w2[d * 3 + 0];
        w2_s[1][d] = s2 * w2[d * 3 + 1];
        w2_s[2][d] = s2 * w2[d * 3 + 2];
    }
    if (tid < 64) {
        w3_s[tid] = w3[tid];
        b3_s[tid] = b3[tid];
        int d = tid >> 1;                      // zero y1 halos
        y1_s[d * 130 + (tid & 1) * 129] = 0.f;
    }
    __syncthreads();

    // ---- Phase B: y1[d][t] -> LDS (lane index t stride-1: conflict-free) ----
    float xm = x_s[tid], x0 = x_s[tid + 1], xp = x_s[tid + 2];
    #pragma unroll
    for (int d = 0; d < 32; ++d) {
        float v = a1_s[0][d] * xm + a1_s[1][d] * x0 + a1_s[2][d] * xp + c1_s[d];
        y1_s[d * 130 + 1 + tid] = fmaxf(v, 0.f);
    }
    __syncthreads();

    // ---- Phase C: y2[t] -> LDS ----
    float s2 = g2[0] * rsqrtf(v2[0] + EPSF);
    float c2 = b2[0] * s2 + be2[0] - m2[0] * s2;
    float acc = c2;
    #pragma unroll
    for (int d = 0; d < 32; ++d) {
        const float* row = &y1_s[d * 130 + tid];
        acc += w2_s[0][d] * row[0] + w2_s[1][d] * row[1] + w2_s[2][d] * row[2];
    }
    y2_s[tid] = fmaxf(acc, 0.f);
    __syncthreads();

    // ---- Phase D: out[o][t] = w3[o]*y2[t]+b3[o], float4 coalesced ----
    float4* out4 = (float4*)(out + (size_t)series * OUT * T);
    #pragma unroll
    for (int i = 0; i < 16; ++i) {
        int flat4 = i * 128 + tid;             // float4 index within series
        int o = flat4 >> 5;                    // (flat4*4)/128
        int t = (flat4 << 2) & 127;
        float4 y = *(const float4*)&y2_s[t];
        float w = w3_s[o], b = b3_s[o];
        out4[flat4] = make_float4(fmaf(w, y.x, b), fmaf(w, y.y, b),
                                  fmaf(w, y.z, b), fmaf(w, y.w, b));
    }
}

extern "C" void kernel_launch(void* const* d_in, const int* in_sizes, int n_in,
                              void* d_out, int out_size, void* d_ws, size_t ws_size,
                              hipStream_t stream) {
    const float* x   = (const float*)d_in[0];   // node_features [B,E,N,T,1]
    // d_in[1] edge_features: unused by the reference computation
    const float* w1  = (const float*)d_in[2];
    const float* b1  = (const float*)d_in[3];
    const float* w2  = (const float*)d_in[4];
    const float* b2  = (const float*)d_in[5];
    const float* w3  = (const float*)d_in[6];
    const float* b3  = (const float*)d_in[7];
    const float* g1  = (const float*)d_in[8];
    const float* be1 = (const float*)d_in[9];
    const float* m1  = (const float*)d_in[10];
    const float* v1  = (const float*)d_in[11];
    const float* g2  = (const float*)d_in[12];
    const float* be2 = (const float*)d_in[13];
    const float* m2  = (const float*)d_in[14];
    const float* v2  = (const float*)d_in[15];

    const int T = 128;
    const int n_series = in_sizes[0] / T;       // 8192

    hnc_kernel<<<n_series, 128, 0, stream>>>(x, w1, b1, w2, b2, w3, b3,
                                             g1, be1, m1, v1, g2, be2, m2, v2,
                                             (float*)d_out);
}